// Round 7
// baseline (159.369 us; speedup 1.0000x reference)
//
#include <hip/hip_runtime.h>

#define HQ 32
#define HKV 8
#define DH 128
#define WIN 256
#define META 128
#define QSCALE 0.1275174324f    // rsqrt(128) * log2(e)  (scores produced in log2 space)
#define NFREQ 0.20762050594046f // log2(10000)/64: invfreq(i) = exp2(-NFREQ*i)

typedef __attribute__((ext_vector_type(8))) __bf16 bf16x8;
typedef __attribute__((ext_vector_type(16))) float f32x16;
typedef __attribute__((ext_vector_type(4))) unsigned int u32x4;
typedef unsigned short u16;
typedef unsigned int u32;

__device__ __forceinline__ u16 f2bf(float f) {
  u32 u = __float_as_uint(f);
  u += 0x7FFFu + ((u >> 16) & 1u);
  return (u16)(u >> 16);
}
__device__ __forceinline__ u32 packbf(float a, float b) {  // a->lo16, b->hi16
  u32 ua = __float_as_uint(a); ua += 0x7FFFu + ((ua >> 16) & 1u);
  u32 ub = __float_as_uint(b); ub += 0x7FFFu + ((ub >> 16) & 1u);
  return (ua >> 16) | (ub & 0xFFFF0000u);
}

// ---------- prep: RoPE(K) -> Kr[hk][s][d] bf16 ; V -> Vt[hk][d][s] bf16 ----------
__global__ __launch_bounds__(256)
void prep_kv(const float* __restrict__ Kg, const float* __restrict__ Vg,
             u16* __restrict__ Kr, u16* __restrict__ Vt, int S) {
  __shared__ float T[64][132];
  const int hk = blockIdx.x;
  const int s0 = blockIdx.y * 64;
  const int tid = threadIdx.x;
  // K rope: 4 threads/row, 16 pairs each
  {
    const int r = tid >> 2, c0 = (tid & 3) * 16;
    const int s = s0 + r;
    const float pos = (float)s;
    const float* src = Kg + ((size_t)s * HKV + hk) * DH;
    u16* dst = Kr + ((size_t)hk * S + s) * DH;
    float x[16], y[16];
    #pragma unroll
    for (int j = 0; j < 16; j += 4) {
      *(float4*)&x[j] = *(const float4*)(src + c0 + j);
      *(float4*)&y[j] = *(const float4*)(src + c0 + 64 + j);
    }
    u16 lo[16], hb[16];
    #pragma unroll
    for (int j = 0; j < 16; ++j) {
      float iv = __builtin_amdgcn_exp2f(-NFREQ * (float)(c0 + j));
      float sv, cv; __sincosf(pos * iv, &sv, &cv);
      lo[j] = f2bf(x[j] * cv - y[j] * sv);
      hb[j] = f2bf(y[j] * cv + x[j] * sv);
    }
    *(int4*)(dst + c0)      = *(int4*)&lo[0];
    *(int4*)(dst + c0 + 8)  = *(int4*)&lo[8];
    *(int4*)(dst + c0 + 64) = *(int4*)&hb[0];
    *(int4*)(dst + c0 + 72) = *(int4*)&hb[8];
  }
  // V transpose: stage fp32, write d-major bf16
  {
    const int r = tid >> 2, c = (tid & 3) * 32;
    const float* src = Vg + ((size_t)(s0 + r) * HKV + hk) * DH + c;
    #pragma unroll
    for (int j = 0; j < 32; j += 4) *(float4*)&T[r][c + j] = *(const float4*)(src + j);
  }
  __syncthreads();
  {
    const int d = tid >> 1, hf = (tid & 1) * 32;
    u16 buf[32];
    #pragma unroll
    for (int i = 0; i < 32; ++i) buf[i] = f2bf(T[hf + i][d]);
    u16* dst = Vt + ((size_t)hk * DH + d) * S + s0 + hf;
    #pragma unroll
    for (int j = 0; j < 4; ++j) *(int4*)(dst + j * 8) = *(int4*)&buf[j * 8];
  }
}

// Register prefetch of next KV tile. NAMED scalars, no arrays/lambdas:
// R2's lambda-captured arrays were alloca'd -> 106 MB scratch traffic.
#define LOAD_KV(kv0_) do {                                                 \
    const int4* ks_ = (const int4*)(Kb + (size_t)((kv0_) + kr) * DH + kc); \
    fk0 = ks_[0]; fk1 = ks_[1]; fk2 = ks_[2]; fk3 = ks_[3];                \
    const int4* vs_ = (const int4*)(Vb + (kv0_));                          \
    fv0 = vs_[0]; fv1 = vs_[1]; fv2 = vs_[2]; fv3 = vs_[3];                \
  } while (0)

#define STORE_KV() do {                                                    \
    int4* kd_ = (int4*)&Ks[kr][kc];                                        \
    kd_[0] = fk0; kd_[1] = fk1; kd_[2] = fk2; kd_[3] = fk3;                \
    int4* vd_ = (int4*)&Vs[tid >> 1][(tid & 1) * 32];                      \
    vd_[0] = fv0; vd_[1] = fv1; vd_[2] = fv2; vd_[3] = fv3;                \
  } while (0)

// ---------- main: flash attention, S^T/O^T orientation (q lives in lanes) ----------
// launch_bounds(256,3): ~170 unified VGPR+AGPR per wave -> 3 blocks/CU ->
// all 544 blocks co-resident (single round, no tail) + 3 decoupled waves/SIMD.
// P-transform split into two halves keeps VGPR <= ~106 (R5 was 108 at 2 waves).
__global__ __launch_bounds__(256, 3)
void attn_main(const float* __restrict__ Qg, const u16* __restrict__ Kr,
               const u16* __restrict__ Vt, float* __restrict__ Og, int S) {
  const int h = blockIdx.x;
  const int nqb = gridDim.y;
  const int q0 = (nqb - 1 - blockIdx.y) * 128;   // heavy blocks (more kv tiles) first
  const int hk = h >> 2;
  const int tid = threadIdx.x;
  const int lane = tid & 63;
  const int wave = tid >> 6;
  const int ln31 = lane & 31;
  const int hi = lane >> 5;
  const int kh = hi * 8;

  // Overlay: prologue Qs[128][136] (34816 B); loop Ks[64][136] + Vs[128][72] (35840 B)
  __shared__ __align__(16) char smem[35840];
  u16 (*Qs)[136] = (u16(*)[136])smem;
  u16 (*Ks)[136] = (u16(*)[136])smem;
  u16 (*Vs)[72]  = (u16(*)[72])(smem + 17408);

  const u16* Kb = Kr + (size_t)hk * S * DH;
  const u16* Vb = Vt + ((size_t)hk * DH + (tid >> 1)) * S + (tid & 1) * 32;
  const int kr = tid >> 2, kc = (tid & 3) * 32;

  int4 fk0, fk1, fk2, fk3, fv0, fv1, fv2, fv3;
  LOAD_KV(0);   // tile-0 loads fly while we do the whole Q prologue

  // ---- prologue: stage Q with RoPE * QSCALE (log2e folded) ----
  {
    const int r = tid >> 1, c0 = (tid & 1) * 32;
    const float pos = (float)(q0 + r);
    const float* qrow = Qg + ((size_t)(q0 + r) * HQ + h) * DH;
    #pragma unroll
    for (int c = c0; c < c0 + 32; c += 8) {
      float x[8], y[8];
      *(float4*)&x[0] = *(const float4*)(qrow + c);
      *(float4*)&x[4] = *(const float4*)(qrow + c + 4);
      *(float4*)&y[0] = *(const float4*)(qrow + c + 64);
      *(float4*)&y[4] = *(const float4*)(qrow + c + 68);
      u16 lo[8], hb[8];
      #pragma unroll
      for (int j = 0; j < 8; ++j) {
        float iv = __builtin_amdgcn_exp2f(-NFREQ * (float)(c + j));
        float sv, cv; __sincosf(pos * iv, &sv, &cv);
        lo[j] = f2bf((x[j] * cv - y[j] * sv) * QSCALE);
        hb[j] = f2bf((y[j] * cv + x[j] * sv) * QSCALE);
      }
      __builtin_memcpy(&Qs[r][c], lo, 16);
      __builtin_memcpy(&Qs[r][c + 64], hb, 16);
    }
  }
  __syncthreads();
  const int qw0 = q0 + wave * 32;
  const int q = qw0 + ln31;           // this lane's q row (S^T col)
  bf16x8 qa[8];                       // B-operand frags: Q[q][k = kh + 16*kk + j]
  {
    const u16* qb = &Qs[wave * 32 + ln31][kh];
    #pragma unroll
    for (int kk = 0; kk < 8; ++kk) qa[kk] = *(const bf16x8*)(qb + kk * 16);
  }
  __syncthreads();   // Qs reads done; region becomes Ks/Vs
  STORE_KV();        // tile 0 into LDS (vmcnt wait covered by prologue)
  __syncthreads();

  int wstart = q0 - WIN; if (wstart < META) wstart = META;
  int nwin = (q0 + 128 - wstart) >> 6; if (nwin < 0) nwin = 0;
  const int ntiles = 2 + nwin;        // meta tiles first (guarantees finite m after t=0)

  f32x16 acc[4];                      // O^T: acc[dt] rows d=dt*32+pattern, col q=lane
  #pragma unroll
  for (int d = 0; d < 4; ++d)
    #pragma unroll
    for (int r = 0; r < 16; ++r) acc[d][r] = 0.f;
  float m_i = -1e30f, l_i = 0.f;      // one scalar per lane(=q row)

  for (int t = 0; t < ntiles; ++t) {
    const int kv0 = (t < 2) ? t * 64 : wstart + (t - 2) * 64;
    const bool haveNext = (t + 1 < ntiles);
    if (haveNext) {                   // issue next tile's loads; ~full tile to land
      const int kvn = (t + 1 < 2) ? (t + 1) * 64 : wstart + (t - 1) * 64;
      LOAD_KV(kvn);
    }

    // wave-active: causal reach AND not window-expired (meta tiles never expire)
    const bool active = (kv0 <= qw0 + 31) &&
                        ((kv0 < META) || (qw0 - kv0 - 63 <= WIN));
    if (active) {
      // ---- S^T = K Q^T : two 32x32 C-tiles (kv rows in regs, q in lanes) ----
      f32x16 s0v, s1v;
      #pragma unroll
      for (int r = 0; r < 16; ++r) { s0v[r] = 0.f; s1v[r] = 0.f; }
      const u16* ka0 = &Ks[ln31][kh];
      const u16* ka1 = &Ks[32 + ln31][kh];
      #pragma unroll
      for (int kk = 0; kk < 8; ++kk)
        s0v = __builtin_amdgcn_mfma_f32_32x32x16_bf16(*(const bf16x8*)(ka0 + kk * 16), qa[kk], s0v, 0, 0, 0);
      #pragma unroll
      for (int kk = 0; kk < 8; ++kk)
        s1v = __builtin_amdgcn_mfma_f32_32x32x16_bf16(*(const bf16x8*)(ka1 + kk * 16), qa[kk], s1v, 0, 0, 0);

      // ---- mask (in-register, per kv value) ----
      const bool fullv = (kv0 + 63 <= qw0) &&
                         ((kv0 + 63 < META) || (qw0 + 31 - kv0 <= WIN));
      if (!fullv) {
        #pragma unroll
        for (int r = 0; r < 16; ++r) {
          const int kva = kv0 + (r & 3) + 8 * (r >> 2) + 4 * hi;
          const int kvb = kva + 32;
          if (!((kva <= q) && (((q - kva) <= WIN) || (kva < META)))) s0v[r] = -1e30f;
          if (!((kvb <= q) && (((q - kvb) <= WIN) || (kvb < META)))) s1v[r] = -1e30f;
        }
      }

      // ---- online softmax: register reduction + ONE cross-half shuffle each ----
      float mx = -1e30f;
      #pragma unroll
      for (int r = 0; r < 16; ++r) mx = fmaxf(mx, fmaxf(s0v[r], s1v[r]));
      mx = fmaxf(mx, __shfl_xor(mx, 32));
      const float mnew = fmaxf(m_i, mx);
      const float al = __builtin_amdgcn_exp2f(m_i - mnew);
      m_i = mnew;
      float ps = 0.f;
      #pragma unroll
      for (int r = 0; r < 16; ++r) {
        s0v[r] = __builtin_amdgcn_exp2f(s0v[r] - mnew);
        s1v[r] = __builtin_amdgcn_exp2f(s1v[r] - mnew);
        ps += s0v[r] + s1v[r];
      }
      ps += __shfl_xor(ps, 32);
      l_i = l_i * al + ps;
      #pragma unroll
      for (int d = 0; d < 4; ++d)
        #pragma unroll
        for (int r = 0; r < 16; ++r) acc[d][r] *= al;

      // ---- P^T transform + PV in TWO HALVES (halves peak VGPR scratch) ----
      // half 0: kv 0..31 (from s0v) -> pbl/pbh -> 8 MFMAs
      {
        u32 pk[8], sh[8];
        #pragma unroll
        for (int m = 0; m < 8; ++m) pk[m] = packbf(s0v[2 * m], s0v[2 * m + 1]);
        #pragma unroll
        for (int m = 0; m < 8; ++m) sh[m] = (u32)__shfl_xor((int)pk[m], 32);
        u32x4 bl = { hi ? sh[2] : pk[0], hi ? sh[3] : pk[1],
                     hi ? pk[2] : sh[0], hi ? pk[3] : sh[1] };
        u32x4 bh = { hi ? sh[6] : pk[4], hi ? sh[7] : pk[5],
                     hi ? pk[6] : sh[4], hi ? pk[7] : sh[5] };
        const bf16x8 pbl = __builtin_bit_cast(bf16x8, bl);
        const bf16x8 pbh = __builtin_bit_cast(bf16x8, bh);
        #pragma unroll
        for (int dt = 0; dt < 4; ++dt) {
          const u16* vrow = &Vs[dt * 32 + ln31][kh];
          acc[dt] = __builtin_amdgcn_mfma_f32_32x32x16_bf16(*(const bf16x8*)(vrow),      pbl, acc[dt], 0, 0, 0);
          acc[dt] = __builtin_amdgcn_mfma_f32_32x32x16_bf16(*(const bf16x8*)(vrow + 16), pbh, acc[dt], 0, 0, 0);
        }
      }
      // half 1: kv 32..63 (from s1v)
      {
        u32 pk[8], sh[8];
        #pragma unroll
        for (int m = 0; m < 8; ++m) pk[m] = packbf(s1v[2 * m], s1v[2 * m + 1]);
        #pragma unroll
        for (int m = 0; m < 8; ++m) sh[m] = (u32)__shfl_xor((int)pk[m], 32);
        u32x4 bl = { hi ? sh[2] : pk[0], hi ? sh[3] : pk[1],
                     hi ? pk[2] : sh[0], hi ? pk[3] : sh[1] };
        u32x4 bh = { hi ? sh[6] : pk[4], hi ? sh[7] : pk[5],
                     hi ? pk[6] : sh[4], hi ? pk[7] : sh[5] };
        const bf16x8 pbl = __builtin_bit_cast(bf16x8, bl);
        const bf16x8 pbh = __builtin_bit_cast(bf16x8, bh);
        #pragma unroll
        for (int dt = 0; dt < 4; ++dt) {
          const u16* vrow = &Vs[dt * 32 + ln31][kh];
          acc[dt] = __builtin_amdgcn_mfma_f32_32x32x16_bf16(*(const bf16x8*)(vrow + 32), pbl, acc[dt], 0, 0, 0);
          acc[dt] = __builtin_amdgcn_mfma_f32_32x32x16_bf16(*(const bf16x8*)(vrow + 48), pbh, acc[dt], 0, 0, 0);
        }
      }
    }

    if (haveNext) {
      __syncthreads();   // all waves done reading Ks/Vs
      STORE_KV();        // prefetched tile -> LDS (loads landed during compute)
      __syncthreads();
    }
  }

  // ---- epilogue: O^T C-layout -> row-major out, 16B stores, one rcp/lane ----
  const float inv = 1.0f / l_i;
  float* ob = Og + ((size_t)q * HQ + h) * DH;
  #pragma unroll
  for (int dt = 0; dt < 4; ++dt) {
    #pragma unroll
    for (int g = 0; g < 4; ++g) {     // d = dt*32 + 8*g + 4*hi + {0..3}
      float4 o = { acc[dt][4 * g + 0] * inv, acc[dt][4 * g + 1] * inv,
                   acc[dt][4 * g + 2] * inv, acc[dt][4 * g + 3] * inv };
      *(float4*)(ob + dt * 32 + 8 * g + 4 * hi) = o;
    }
  }
}

extern "C" void kernel_launch(void* const* d_in, const int* in_sizes, int n_in,
                              void* d_out, int out_size, void* d_ws, size_t ws_size,
                              hipStream_t stream) {
  const float* Qg = (const float*)d_in[0];
  const float* Kg = (const float*)d_in[1];
  const float* Vg = (const float*)d_in[2];
  float* Og = (float*)d_out;
  const int S = in_sizes[0] / (HQ * DH);   // 2176

  u16* Kr = (u16*)d_ws;                                     // 8*S*128 bf16 = 4.45 MB
  u16* Vt = (u16*)((char*)d_ws + (size_t)HKV * S * DH * 2); // 4.45 MB

  prep_kv<<<dim3(HKV, S / 64), dim3(256), 0, stream>>>(Kg, Vg, Kr, Vt, S);
  attn_main<<<dim3(HQ, S / 128), dim3(256), 0, stream>>>(Qg, Kr, Vt, Og, S);
}

// Round 8
// 131.522 us; speedup vs baseline: 1.2117x; 1.2117x over previous
//
#include <hip/hip_runtime.h>

#define HQ 32
#define HKV 8
#define DH 128
#define WIN 256
#define META 128
#define QSCALE 0.1275174324f    // rsqrt(128) * log2(e)  (scores produced in log2 space)
#define NFREQ 0.20762050594046f // log2(10000)/64: invfreq(i) = exp2(-NFREQ*i)

typedef __attribute__((ext_vector_type(8))) __bf16 bf16x8;
typedef __attribute__((ext_vector_type(4))) float f32x4;
typedef unsigned short u16;
typedef unsigned int u32;

__device__ __forceinline__ u16 f2bf(float f) {
  u32 u = __float_as_uint(f);
  u += 0x7FFFu + ((u >> 16) & 1u);
  return (u16)(u >> 16);
}
__device__ __forceinline__ u32 packbf(float a, float b) {  // a->lo16, b->hi16
  u32 ua = __float_as_uint(a); ua += 0x7FFFu + ((ua >> 16) & 1u);
  u32 ub = __float_as_uint(b); ub += 0x7FFFu + ((ub >> 16) & 1u);
  return (ua >> 16) | (ub & 0xFFFF0000u);
}

// ---------- prep: RoPE(K) -> Kr[hk][s][d] bf16 ; V -> Vt[hk][d][s] bf16 ----------
__global__ __launch_bounds__(256)
void prep_kv(const float* __restrict__ Kg, const float* __restrict__ Vg,
             u16* __restrict__ Kr, u16* __restrict__ Vt, int S) {
  __shared__ float T[64][132];
  const int hk = blockIdx.x;
  const int s0 = blockIdx.y * 64;
  const int tid = threadIdx.x;
  {
    const int r = tid >> 2, c0 = (tid & 3) * 16;
    const int s = s0 + r;
    const float pos = (float)s;
    const float* src = Kg + ((size_t)s * HKV + hk) * DH;
    u16* dst = Kr + ((size_t)hk * S + s) * DH;
    float x[16], y[16];
    #pragma unroll
    for (int j = 0; j < 16; j += 4) {
      *(float4*)&x[j] = *(const float4*)(src + c0 + j);
      *(float4*)&y[j] = *(const float4*)(src + c0 + 64 + j);
    }
    u16 lo[16], hb[16];
    #pragma unroll
    for (int j = 0; j < 16; ++j) {
      float iv = __builtin_amdgcn_exp2f(-NFREQ * (float)(c0 + j));
      float sv, cv; __sincosf(pos * iv, &sv, &cv);
      lo[j] = f2bf(x[j] * cv - y[j] * sv);
      hb[j] = f2bf(y[j] * cv + x[j] * sv);
    }
    *(int4*)(dst + c0)      = *(int4*)&lo[0];
    *(int4*)(dst + c0 + 8)  = *(int4*)&lo[8];
    *(int4*)(dst + c0 + 64) = *(int4*)&hb[0];
    *(int4*)(dst + c0 + 72) = *(int4*)&hb[8];
  }
  {
    const int r = tid >> 2, c = (tid & 3) * 32;
    const float* src = Vg + ((size_t)(s0 + r) * HKV + hk) * DH + c;
    #pragma unroll
    for (int j = 0; j < 32; j += 4) *(float4*)&T[r][c + j] = *(const float4*)(src + j);
  }
  __syncthreads();
  {
    const int d = tid >> 1, hf = (tid & 1) * 32;
    u16 buf[32];
    #pragma unroll
    for (int i = 0; i < 32; ++i) buf[i] = f2bf(T[hf + i][d]);
    u16* dst = Vt + ((size_t)hk * DH + d) * S + s0 + hf;
    #pragma unroll
    for (int j = 0; j < 4; ++j) *(int4*)(dst + j * 8) = *(int4*)&buf[j * 8];
  }
}

// Register prefetch of next KV tile. NAMED scalars (no arrays/lambdas: R2 alloca trap).
#define LOAD_KV(kv0_) do {                                                 \
    const int4* ks_ = (const int4*)(Kb + (size_t)((kv0_) + kr) * DH + kc); \
    fk0 = ks_[0]; fk1 = ks_[1]; fk2 = ks_[2]; fk3 = ks_[3];                \
    const int4* vs_ = (const int4*)(Vb + (kv0_));                          \
    fv0 = vs_[0]; fv1 = vs_[1]; fv2 = vs_[2]; fv3 = vs_[3];                \
  } while (0)

#define STORE_KV() do {                                                    \
    int4* kd_ = (int4*)&Ks[kr][kc];                                        \
    kd_[0] = fk0; kd_[1] = fk1; kd_[2] = fk2; kd_[3] = fk3;                \
    int4* vd_ = (int4*)&Vs[tid >> 1][(tid & 1) * 32];                      \
    vd_[0] = fv0; vd_[1] = fv1; vd_[2] = fv2; vd_[3] = fv3;                \
  } while (0)

// ---------- main: flash attention, S^T/O^T, 16 q-rows per wave (16x16x32 MFMA) ----------
// Per-wave: acc 32 AGPR + ~110 VGPR -> 3 waves/SIMD; grid 1088 blocks = 4.25/CU
// feeds 3 blocks/CU (LDS 44 KB x 3 = 132 KB). P transform via wave-private LDS
// (in-order DS, no barrier). Named-scalar prefetch as R5.
__global__ __launch_bounds__(256, 3)
void attn_main(const float* __restrict__ Qg, const u16* __restrict__ Kr,
               const u16* __restrict__ Vt, float* __restrict__ Og, int S) {
  const int h = blockIdx.x;
  const int nqb = gridDim.y;
  const int q0 = (nqb - 1 - blockIdx.y) * 64;   // heavy blocks first
  const int hk = h >> 2;
  const int tid = threadIdx.x;
  const int lane = tid & 63;
  const int wave = tid >> 6;
  const int qid  = lane & 15;      // q col within wave tile (C/D n-index)
  const int quad = lane >> 4;      // 0..3
  const int k8   = quad * 8;       // A/B-frag k offset within a 32-chunk

  // Overlay: prologue Qs[64][136] (17408 B); loop Ks 17408 + Vs 18432 + Ps 9216 = 45056 B
  __shared__ __align__(16) char smem[45056];
  u16 (*Qs)[136] = (u16(*)[136])smem;
  u16 (*Ks)[136] = (u16(*)[136])smem;
  u16 (*Vs)[72]  = (u16(*)[72])(smem + 17408);
  u16 (*Ps)[72]  = (u16(*)[72])(smem + 35840);   // row = wave*16 + q

  const u16* Kb = Kr + (size_t)hk * S * DH;
  const u16* Vb = Vt + ((size_t)hk * DH + (tid >> 1)) * S + (tid & 1) * 32;
  const int kr = tid >> 2, kc = (tid & 3) * 32;

  int4 fk0, fk1, fk2, fk3, fv0, fv1, fv2, fv3;
  LOAD_KV(0);   // tile-0 loads fly during the Q prologue

  // ---- prologue: stage Q (64 rows) with RoPE * QSCALE ----
  {
    const int r = tid >> 2, c0 = (tid & 3) * 16;
    const float pos = (float)(q0 + r);
    const float* qrow = Qg + ((size_t)(q0 + r) * HQ + h) * DH;
    float x[16], y[16];
    #pragma unroll
    for (int j = 0; j < 16; j += 4) {
      *(float4*)&x[j] = *(const float4*)(qrow + c0 + j);
      *(float4*)&y[j] = *(const float4*)(qrow + c0 + 64 + j);
    }
    u16 lo[16], hb[16];
    #pragma unroll
    for (int j = 0; j < 16; ++j) {
      float iv = __builtin_amdgcn_exp2f(-NFREQ * (float)(c0 + j));
      float sv, cv; __sincosf(pos * iv, &sv, &cv);
      lo[j] = f2bf((x[j] * cv - y[j] * sv) * QSCALE);
      hb[j] = f2bf((y[j] * cv + x[j] * sv) * QSCALE);
    }
    *(int4*)(&Qs[r][c0])      = *(int4*)&lo[0];
    *(int4*)(&Qs[r][c0 + 8])  = *(int4*)&lo[8];
    *(int4*)(&Qs[r][c0 + 64]) = *(int4*)&hb[0];
    *(int4*)(&Qs[r][c0 + 72]) = *(int4*)&hb[8];
  }
  __syncthreads();
  const int qw0 = q0 + wave * 16;
  const int q   = qw0 + qid;          // this lane's q row
  bf16x8 qa[4];                       // B-frags: Q[q][32c + k8 + j]
  {
    const u16* qb = &Qs[wave * 16 + qid][k8];
    #pragma unroll
    for (int c = 0; c < 4; ++c) qa[c] = *(const bf16x8*)(qb + 32 * c);
  }
  __syncthreads();   // Qs dead; region becomes Ks/Vs
  STORE_KV();        // tile 0 -> LDS
  __syncthreads();

  int wstart = q0 - WIN; if (wstart < META) wstart = META;
  int nwin = (q0 + 64 - wstart) >> 6; if (nwin < 0) nwin = 0;
  const int ntiles = 2 + nwin;        // meta tiles first

  f32x4 acc[8];                       // O^T: acc[D], d = 16D + 4*quad + r, col q
  #pragma unroll
  for (int D = 0; D < 8; ++D)
    #pragma unroll
    for (int r = 0; r < 4; ++r) acc[D][r] = 0.f;
  float m_i = -1e30f, l_i = 0.f;      // l_i is a quad-partial; combined in epilogue

  for (int t = 0; t < ntiles; ++t) {
    const int kv0 = (t < 2) ? t * 64 : wstart + (t - 2) * 64;
    const bool haveNext = (t + 1 < ntiles);
    if (haveNext) {
      const int kvn = (t + 1 < 2) ? (t + 1) * 64 : wstart + (t - 1) * 64;
      LOAD_KV(kvn);
    }

    const bool active = (kv0 <= qw0 + 15) &&
                        ((kv0 < META) || (qw0 - kv0 - 63 <= WIN));
    if (active) {
      // ---- S^T = K Q^T : 4 16x16 C-tiles over kv, K=128 in 4 chunks ----
      f32x4 sv[4];
      #pragma unroll
      for (int T = 0; T < 4; ++T)
        #pragma unroll
        for (int r = 0; r < 4; ++r) sv[T][r] = 0.f;
      #pragma unroll
      for (int T = 0; T < 4; ++T) {
        const u16* ka = &Ks[16 * T + qid][k8];
        #pragma unroll
        for (int c = 0; c < 4; ++c)
          sv[T] = __builtin_amdgcn_mfma_f32_16x16x32_bf16(
                    *(const bf16x8*)(ka + 32 * c), qa[c], sv[T], 0, 0, 0);
      }

      // ---- mask (per element: kv = kv0 + 16T + 4*quad + r) ----
      const bool fullv = (kv0 + 63 <= qw0) &&
                         ((kv0 + 63 < META) || (qw0 + 15 - kv0 <= WIN));
      if (!fullv) {
        #pragma unroll
        for (int T = 0; T < 4; ++T) {
          #pragma unroll
          for (int r = 0; r < 4; ++r) {
            const int kv = kv0 + 16 * T + 4 * quad + r;
            if (!((kv <= q) && (((q - kv) <= WIN) || (kv < META)))) sv[T][r] = -1e30f;
          }
        }
      }

      // ---- online softmax: reg reduce + 2 cross-quad shuffles for max ----
      float mx = -1e30f;
      #pragma unroll
      for (int T = 0; T < 4; ++T)
        #pragma unroll
        for (int r = 0; r < 4; ++r) mx = fmaxf(mx, sv[T][r]);
      mx = fmaxf(mx, __shfl_xor(mx, 16));
      mx = fmaxf(mx, __shfl_xor(mx, 32));
      const float mnew = fmaxf(m_i, mx);
      const float al = __builtin_amdgcn_exp2f(m_i - mnew);
      m_i = mnew;
      float ps = 0.f;
      #pragma unroll
      for (int T = 0; T < 4; ++T)
        #pragma unroll
        for (int r = 0; r < 4; ++r) {
          sv[T][r] = __builtin_amdgcn_exp2f(sv[T][r] - mnew);
          ps += sv[T][r];
        }
      l_i = l_i * al + ps;            // quad-partial sum (m shared => consistent)
      #pragma unroll
      for (int D = 0; D < 8; ++D)
        #pragma unroll
        for (int r = 0; r < 4; ++r) acc[D][r] *= al;

      // ---- P: C-layout -> B-layout via wave-private LDS (in-order, no barrier) ----
      {
        u32* pw = (u32*)&Ps[wave * 16 + qid][0];
        #pragma unroll
        for (int T = 0; T < 4; ++T) {
          pw[8 * T + 2 * quad]     = packbf(sv[T][0], sv[T][1]);
          pw[8 * T + 2 * quad + 1] = packbf(sv[T][2], sv[T][3]);
        }
      }
      const u16* pb = &Ps[wave * 16 + qid][k8];
      const bf16x8 p0 = *(const bf16x8*)(pb);        // kv chunk 0 (0..31)
      const bf16x8 p1 = *(const bf16x8*)(pb + 32);   // kv chunk 1 (32..63)

      // ---- O^T += V^T P^T : 8 d-tiles x 2 kv-chunks ----
      #pragma unroll
      for (int D = 0; D < 8; ++D) {
        const u16* va = &Vs[16 * D + qid][k8];
        acc[D] = __builtin_amdgcn_mfma_f32_16x16x32_bf16(*(const bf16x8*)(va),      p0, acc[D], 0, 0, 0);
        acc[D] = __builtin_amdgcn_mfma_f32_16x16x32_bf16(*(const bf16x8*)(va + 32), p1, acc[D], 0, 0, 0);
      }
    }

    if (haveNext) {
      __syncthreads();   // all waves done reading Ks/Vs
      STORE_KV();        // prefetched tile -> LDS
      __syncthreads();
    }
  }

  // ---- epilogue: combine quad-partial l, scale, 16B stores ----
  l_i += __shfl_xor(l_i, 16);
  l_i += __shfl_xor(l_i, 32);
  const float inv = 1.0f / l_i;
  float* ob = Og + ((size_t)q * HQ + h) * DH;
  #pragma unroll
  for (int D = 0; D < 8; ++D) {       // d = 16D + 4*quad + {0..3}
    float4 o = { acc[D][0] * inv, acc[D][1] * inv, acc[D][2] * inv, acc[D][3] * inv };
    *(float4*)(ob + 16 * D + 4 * quad) = o;
  }
}

extern "C" void kernel_launch(void* const* d_in, const int* in_sizes, int n_in,
                              void* d_out, int out_size, void* d_ws, size_t ws_size,
                              hipStream_t stream) {
  const float* Qg = (const float*)d_in[0];
  const float* Kg = (const float*)d_in[1];
  const float* Vg = (const float*)d_in[2];
  float* Og = (float*)d_out;
  const int S = in_sizes[0] / (HQ * DH);   // 2176

  u16* Kr = (u16*)d_ws;                                     // 4.45 MB
  u16* Vt = (u16*)((char*)d_ws + (size_t)HKV * S * DH * 2); // 4.45 MB

  prep_kv<<<dim3(HKV, S / 64), dim3(256), 0, stream>>>(Kg, Vg, Kr, Vt, S);
  attn_main<<<dim3(HQ, S / 64), dim3(256), 0, stream>>>(Qg, Kr, Vt, Og, S);
}